// Round 4
// baseline (819.157 us; speedup 1.0000x reference)
//
#include <hip/hip_runtime.h>
#include <hip/hip_bf16.h>

#define NTOK  65536   // B*S = 64*1024
#define CIN   768
#define NDIM  8
#define NLVL  15
#define NSLOT 8       // KDE atomic slot arrays (contention spread)
#define TOKPB 64      // tokens per block (kernel A)
#define KCH   64      // channels per K-chunk
#define NCHK  12      // 768 / 64

// ---------------------------------------------------------------------------
// Kernel A (round-5): LDS-staged, occupancy-first.
//   thread = (token = lane, dim-pair = wave): wave w owns dims {2w, 2w+1}
//   for all 64 tokens of the block; acc is 2 f64 regs. No shuffle collapse
//   (cross-wave dim reassembly happens ONCE via LDS at the end).
//   z: cooperatively staged (coalesced 64B segments) into LDS in 64-ch
//   chunks, double-buffered with T14 split (issue loads -> compute -> LDS
//   write -> barrier). 65-float row pad + scalar b32 reads: conflict-free,
//   and 65-word stride makes b128 illegal anyway (not 16B aligned).
//   Wc: NOT in VGPRs (round-0/2: 96-reg array capped occupancy at 2
//   waves/SIMD; round-1: widening it spilled). Wave-uniform float4 loads
//   from global (24KB, L1-resident), cvt f64 per use.
//   38.75KB LDS, ~80 VGPR -> 4 blocks/CU -> 4 waves/SIMD (2x prior rounds).
// round-3 lesson: token-per-lane DIRECT global reads are uncoalesced
//   (3072B lane stride) — staging via LDS is mandatory for this layout.
// round-1 lesson: >~230 live VGPRs at (256,2) = spill catastrophe.
// round-2 keeper: f32 KDE exp of f32-rounded zc (absmax-identical); zc
//   itself stays f64 for the argmin.
// ---------------------------------------------------------------------------
__global__ __launch_bounds__(256, 4)
void fsq_compress_kde(const float* __restrict__ z, const float* __restrict__ Wc,
                      const float* __restrict__ bc, const float* __restrict__ centers,
                      float* out, double* __restrict__ kde_slots)
{
    __shared__ float  zt[2][TOKPB][KCH + 1];   // 33.3 KiB (65-pad)
    __shared__ double zst[TOKPB][NDIM];        // 4 KiB   (f64 zc assembly)
    __shared__ float  zc32[TOKPB][NDIM + 1];   // 2.25 KiB (KDE source)

    const int tid  = threadIdx.x;
    const int lane = tid & 63;
    const int wv   = tid >> 6;               // 0..3 -> dims 2wv, 2wv+1
    const int tok0 = blockIdx.x * TOKPB;

    // staging map: 4 threads per token row, 16B quarter each, 4 x 64B steps
    const int    srow = tid >> 2;            // 0..63
    const int    sq   = tid & 3;             // 0..3
    const float* zsrc = z + (size_t)(tok0 + srow) * CIN + sq * 4;

    const int    d0  = wv * 2;
    const double bs0 = (double)bc[d0];
    const double bs1 = (double)bc[d0 + 1];
    const float* w0p = Wc + d0 * CIN;        // dim d0 weight row
    const float* w1p = w0p + CIN;            // dim d0+1 weight row

#define ZSTORE(BUF, V, J)                                                   \
    {                                                                       \
        zt[BUF][srow][sq * 4 + 16 * (J) + 0] = (V).x;                       \
        zt[BUF][srow][sq * 4 + 16 * (J) + 1] = (V).y;                       \
        zt[BUF][srow][sq * 4 + 16 * (J) + 2] = (V).z;                       \
        zt[BUF][srow][sq * 4 + 16 * (J) + 3] = (V).w;                       \
    }

    // prologue: stage chunk 0 into buffer 0
    {
        const float4 t0 = *(const float4*)(zsrc +  0);
        const float4 t1 = *(const float4*)(zsrc + 16);
        const float4 t2 = *(const float4*)(zsrc + 32);
        const float4 t3 = *(const float4*)(zsrc + 48);
        ZSTORE(0, t0, 0) ZSTORE(0, t1, 1) ZSTORE(0, t2, 2) ZSTORE(0, t3, 3)
    }
    __syncthreads();

    double acc0 = 0.0, acc1 = 0.0;

#pragma unroll 1
    for (int ch = 0; ch < NCHK; ++ch) {
        const int  cur  = ch & 1;
        const bool more = (ch + 1 < NCHK);

        // T14 split: issue next-chunk global loads first (in flight during
        // compute), LDS-write them after compute, one barrier per chunk.
        float4 t0, t1, t2, t3;
        if (more) {
            const float* zs = zsrc + (ch + 1) * KCH;
            t0 = *(const float4*)(zs +  0);
            t1 = *(const float4*)(zs + 16);
            t2 = *(const float4*)(zs + 32);
            t3 = *(const float4*)(zs + 48);
        }

        // compute on buffer cur: this lane's token row, dims d0, d0+1
        const float* zr  = &zt[cur][lane][0];
        const float* wp0 = w0p + ch * KCH;
        const float* wp1 = w1p + ch * KCH;
#pragma unroll
        for (int c = 0; c < KCH; c += 4) {
            const float z0 = zr[c + 0], z1 = zr[c + 1];
            const float z2 = zr[c + 2], z3 = zr[c + 3];
            const double x0 = (double)z0, x1 = (double)z1;
            const double x2 = (double)z2, x3 = (double)z3;
            const float4 wa = *(const float4*)(wp0 + c);   // wave-uniform
            const float4 wb = *(const float4*)(wp1 + c);   // (L1 broadcast)
            acc0 = fma(x0, (double)wa.x, acc0);
            acc0 = fma(x1, (double)wa.y, acc0);
            acc0 = fma(x2, (double)wa.z, acc0);
            acc0 = fma(x3, (double)wa.w, acc0);
            acc1 = fma(x0, (double)wb.x, acc1);
            acc1 = fma(x1, (double)wb.y, acc1);
            acc1 = fma(x2, (double)wb.z, acc1);
            acc1 = fma(x3, (double)wb.w, acc1);
        }

        if (more) {
            ZSTORE(cur ^ 1, t0, 0) ZSTORE(cur ^ 1, t1, 1)
            ZSTORE(cur ^ 1, t2, 2) ZSTORE(cur ^ 1, t3, 3)
        }
        __syncthreads();
    }
#undef ZSTORE

    // finalize zc for (token=lane, dims d0,d0+1); reassemble rows in LDS
    acc0 += bs0;
    acc1 += bs1;
    {
        double2 v; v.x = acc0; v.y = acc1;
        *(double2*)&zst[lane][d0] = v;             // 16B aligned (d0 even)
        zc32[lane][d0]     = (float)acc0;
        zc32[lane][d0 + 1] = (float)acc1;
    }
    __syncthreads();

    // wave 0: stash f64 zc into the 64B row head of out (read by kernel C)
    if (tid < TOKPB) {
        double* orow = (double*)(out + (size_t)(tok0 + tid) * CIN);
#pragma unroll
        for (int i = 0; i < 4; ++i)
            *((double2*)orow + i) = *(const double2*)&zst[tid][2 * i];
    }

    // waves 2-3: KDE over this block's 64 tokens. thread -> (dim, level).
    if (tid >= 128) {
        const int idx = tid - 128;         // 0..127
        const int d2  = idx >> 4;          // 0..7
        const int l2  = idx & 15;          // 0..15 (15 = idle)
        if (l2 < NLVL) {
            const float c = centers[d2 * NLVL + l2];
            double k = 0.0;
#pragma unroll 4
            for (int t = 0; t < TOKPB; ++t) {
                const float df = c - zc32[t][d2];
                k += (double)__expf(df * df * -2.0f);  // exp(-0.5*((c-s)/.5)^2)
            }
            double* slot = kde_slots + (blockIdx.x & (NSLOT - 1)) * 128;
            unsafeAtomicAdd(&slot[d2 * NLVL + l2], k);
        }
    }
}

// ---------------------------------------------------------------------------
// Kernel C: recompute scaled centers in LDS (fused scale step), f64 argmin
// per (token, dim), fp32 expand z_q = q @ We^T + be. Reads zc from the row
// heads this wave later overwrites (load-before-store within the wave).
// launch_bounds(256,2): We's 96-reg array must not spill (round-2 lesson).
// Unchanged: ~40us vs ~31us write floor (76% of roofline), proven correct.
// ---------------------------------------------------------------------------
__global__ __launch_bounds__(256, 2)
void fsq_quant_expand(const double* __restrict__ kde_slots,
                      const float* __restrict__ centers,
                      const float* __restrict__ We, const float* __restrict__ be,
                      float* out, float* out_scalar)
{
    __shared__ double w_lds[NDIM * NLVL];
    __shared__ double sc_lds[NDIM * NLVL];
    {
        const int t = threadIdx.x;
        if (t < NDIM * NLVL) {
            double a = 0.0;
#pragma unroll
            for (int k = 0; k < NSLOT; ++k) a += kde_slots[k * 128 + t];
            w_lds[t] = a * (1.0 / 65536.0) + 1e-6;
        }
        __syncthreads();
        if (t < NDIM * NLVL) {
            const int d = t / NLVL;
            double s = 0.0;
#pragma unroll
            for (int l = 0; l < NLVL; ++l) s += w_lds[d * NLVL + l];
            sc_lds[t] = (double)centers[t] * (w_lds[t] / s);
        }
        if (blockIdx.x == 0 && t == 0) *out_scalar = 0.0f;
        __syncthreads();
    }

    const int lane  = threadIdx.x & 63;
    const int gwave = blockIdx.x * 4 + (threadIdx.x >> 6);
    const int base  = gwave * 8;

    // We in fp32 regs: channel c = lane*4 + 256*m + k
    float Wer[12][NDIM];
    float ber[12];
#pragma unroll
    for (int m = 0; m < 3; ++m) {
#pragma unroll
        for (int k = 0; k < 4; ++k) {
            const int    c  = lane * 4 + 256 * m + k;
            const float4 u0 = *(const float4*)(We + c * NDIM);
            const float4 u1 = *(const float4*)(We + c * NDIM + 4);
            Wer[m * 4 + k][0] = u0.x; Wer[m * 4 + k][1] = u0.y;
            Wer[m * 4 + k][2] = u0.z; Wer[m * 4 + k][3] = u0.w;
            Wer[m * 4 + k][4] = u1.x; Wer[m * 4 + k][5] = u1.y;
            Wer[m * 4 + k][6] = u1.z; Wer[m * 4 + k][7] = u1.w;
            ber[m * 4 + k] = be[c];
        }
    }

    const int dsel = lane & 7;      // this lane's dim
    const int tsel = lane >> 3;     // this lane's token within the group of 8

    // one zc value per lane: (token base+tsel, dim dsel) — before any store
    double zd;
    __builtin_memcpy(&zd, out + (size_t)(base + tsel) * CIN + 2 * dsel, 8);

    // first-min argmin over the 15 scaled centers of dim dsel (matches np)
    const double* sc = sc_lds + dsel * NLVL;
    double best = fabs(zd - sc[0]);
    double q    = sc[0];
#pragma unroll
    for (int l = 1; l < NLVL; ++l) {
        const double dd = fabs(zd - sc[l]);
        if (dd < best) { best = dd; q = sc[l]; }
    }
    const float qf = (float)q;

#pragma unroll 1
    for (int t = 0; t < 8; ++t) {
        float qa[NDIM];
#pragma unroll
        for (int j = 0; j < NDIM; ++j) qa[j] = __shfl(qf, t * 8 + j, 64);

        float* op = out + (size_t)(base + t) * CIN;
#pragma unroll
        for (int m = 0; m < 3; ++m) {
            float v[4];
#pragma unroll
            for (int k = 0; k < 4; ++k) {
                float s = ber[m * 4 + k];
#pragma unroll
                for (int j = 0; j < NDIM; ++j)
                    s = fmaf(qa[j], Wer[m * 4 + k][j], s);
                v[k] = s;
            }
            *(float4*)(op + m * 256 + lane * 4) = make_float4(v[0], v[1], v[2], v[3]);
        }
    }
}

// ---------------------------------------------------------------------------
extern "C" void kernel_launch(void* const* d_in, const int* in_sizes, int n_in,
                              void* d_out, int out_size, void* d_ws, size_t ws_size,
                              hipStream_t stream)
{
    const float* z       = (const float*)d_in[0];
    const float* Wc      = (const float*)d_in[1];
    const float* bc      = (const float*)d_in[2];
    const float* We      = (const float*)d_in[3];
    const float* be      = (const float*)d_in[4];
    const float* centers = (const float*)d_in[5];
    float*       out     = (float*)d_out;

    double* kde_slots = (double*)d_ws;   // NSLOT x 128 doubles = 8 KB

    hipMemsetAsync(kde_slots, 0, NSLOT * 128 * sizeof(double), stream);
    fsq_compress_kde<<<NTOK / TOKPB, 256, 0, stream>>>(z, Wc, bc, centers, out,
                                                       kde_slots);
    fsq_quant_expand<<<2048, 256, 0, stream>>>(kde_slots, centers, We, be, out,
                                               out + (size_t)out_size - 1);
}

// Round 5
// 404.491 us; speedup vs baseline: 2.0252x; 2.0252x over previous
//
#include <hip/hip_runtime.h>
#include <hip/hip_bf16.h>

#define NTOK 65536   // B*S = 64*1024
#define CIN  768
#define NDIM 8
#define NLVL 15
#define NSLOT 8      // KDE atomic slot arrays (contention spread)

// ---------------------------------------------------------------------------
// Kernel A: zc = z @ Wc^T + bc (f64 accum, fp32 weights in VGPRs, cvt per use),
// stash zc (f64 bits) into first 64B of each out row, accumulate KDE sums
// via collapse-transpose wave reduction + slotted f64 atomics.
// 2048 blocks x 4 waves; each wave owns 8 consecutive tokens.
//
// Round-6 change: ONE-TOKEN SKEW. Token t's 6-level f64 shuffle collapse
// (~6 serial ds_bpermute round-trips) is placed in the same basic block as
// token t+1's FMA phase (independent work) so the scheduler interleaves
// them instead of serializing ~500cy FMA + ~700cy collapse per token.
// Two named acc arrays (accA/accB, static indices only — rule #20), peeled
// prologue, branch-free pair loop.
//
// Register law (empirical, rounds 1/2/4): __launch_bounds__(256,w) hard-caps
// VGPRs at ~512/(2w): (256,3)->84, (256,2)->128. R0 fit under 128; R1's
// widened pair loop (~194 live) spilled 422MB at (256,2). This version needs
// ~174 live -> plain __launch_bounds__(256) (cap 512). Occupancy stays
// 2 waves/SIMD either way (512/174).
// round-3 lesson: never give up coalesced row reads for z.
// round-4 lesson: never move Wc out of VGPRs into per-wave global streams
//   (10x HBM amplification, A=530us).
// round-2 keeper: f32 KDE exp of f32-rounded zc (absmax-identical); zc
//   itself stays f64 for the argmin.
// ---------------------------------------------------------------------------
__global__ __launch_bounds__(256)
void fsq_compress_kde(const float* __restrict__ z, const float* __restrict__ Wc,
                      const float* __restrict__ bc, const float* __restrict__ centers,
                      float* out, double* __restrict__ kde_slots)
{
    const int lane  = threadIdx.x & 63;
    const int gwave = blockIdx.x * 4 + (threadIdx.x >> 6);   // 0..8191
    const int base  = gwave * 8;

    // Wc in fp32 regs: Wcf[d][m*4+k] for channel c = 4*lane + 256*m + k
    float Wcf[NDIM][12];
#pragma unroll
    for (int d = 0; d < NDIM; ++d) {
#pragma unroll
        for (int m = 0; m < 3; ++m) {
            const float4 w4 = *(const float4*)(Wc + d * CIN + m * 256 + lane * 4);
            Wcf[d][m * 4 + 0] = w4.x;
            Wcf[d][m * 4 + 1] = w4.y;
            Wcf[d][m * 4 + 2] = w4.z;
            Wcf[d][m * 4 + 3] = w4.w;
        }
    }

    const int    dsel = lane & 7;     // this lane's dim after collapse
    const int    lsel = lane >> 3;    // this lane's KDE level (and stash token)
    const double bsel = (double)bc[dsel];
    const bool   hasB = (lsel < 7);
    const float  cA   = centers[dsel * NLVL + lsel];
    const float  cB   = hasB ? centers[dsel * NLVL + lsel + 8] : 0.0f;

    const int b0 = lane & 1, b1 = lane & 2, b2 = lane & 4;

    float  kA = 0.0f, kB = 0.0f;
    double zst = 0.0;

    const float* zb = z + (size_t)base * CIN;

// load token T's 768-channel row slice for this lane (3 x float4)
#define ZLOAD(D0, D1, D2, T)                                                \
    {                                                                       \
        const float* zp_ = zb + (size_t)(T) * CIN;                          \
        D0 = *(const float4*)(zp_ + lane * 4);                              \
        D1 = *(const float4*)(zp_ + 256 + lane * 4);                        \
        D2 = *(const float4*)(zp_ + 512 + lane * 4);                        \
    }

// 96 f64 FMAs of one token into ACC (zeroed first)
#define FMATOK(A0, A1, A2, ACC)                                             \
    {                                                                       \
        _Pragma("unroll")                                                   \
        for (int d_ = 0; d_ < NDIM; ++d_) ACC[d_] = 0.0;                    \
        {                                                                   \
            const double x0 = (double)A0.x, x1 = (double)A0.y;              \
            const double x2 = (double)A0.z, x3 = (double)A0.w;              \
            _Pragma("unroll")                                               \
            for (int d_ = 0; d_ < NDIM; ++d_) {                             \
                ACC[d_] = fma(x0, (double)Wcf[d_][0], ACC[d_]);             \
                ACC[d_] = fma(x1, (double)Wcf[d_][1], ACC[d_]);             \
                ACC[d_] = fma(x2, (double)Wcf[d_][2], ACC[d_]);             \
                ACC[d_] = fma(x3, (double)Wcf[d_][3], ACC[d_]);             \
            }                                                               \
        }                                                                   \
        {                                                                   \
            const double x0 = (double)A1.x, x1 = (double)A1.y;              \
            const double x2 = (double)A1.z, x3 = (double)A1.w;              \
            _Pragma("unroll")                                               \
            for (int d_ = 0; d_ < NDIM; ++d_) {                             \
                ACC[d_] = fma(x0, (double)Wcf[d_][4], ACC[d_]);             \
                ACC[d_] = fma(x1, (double)Wcf[d_][5], ACC[d_]);             \
                ACC[d_] = fma(x2, (double)Wcf[d_][6], ACC[d_]);             \
                ACC[d_] = fma(x3, (double)Wcf[d_][7], ACC[d_]);             \
            }                                                               \
        }                                                                   \
        {                                                                   \
            const double x0 = (double)A2.x, x1 = (double)A2.y;              \
            const double x2 = (double)A2.z, x3 = (double)A2.w;              \
            _Pragma("unroll")                                               \
            for (int d_ = 0; d_ < NDIM; ++d_) {                             \
                ACC[d_] = fma(x0, (double)Wcf[d_][8],  ACC[d_]);            \
                ACC[d_] = fma(x1, (double)Wcf[d_][9],  ACC[d_]);            \
                ACC[d_] = fma(x2, (double)Wcf[d_][10], ACC[d_]);            \
                ACC[d_] = fma(x3, (double)Wcf[d_][11], ACC[d_]);            \
            }                                                               \
        }                                                                   \
    }

// collapse-transpose ACC (8 accs over 64 lanes -> lane's dim = lane&7),
// then stash-check + f32 KDE for token T
#define COLLAPSE(ACC, T)                                                    \
    {                                                                       \
        double r_[4];                                                       \
        _Pragma("unroll")                                                   \
        for (int j_ = 0; j_ < 4; ++j_) {                                    \
            const double snd_ = b0 ? ACC[2 * j_] : ACC[2 * j_ + 1];         \
            const double kp_  = b0 ? ACC[2 * j_ + 1] : ACC[2 * j_];         \
            r_[j_] = kp_ + __shfl_xor(snd_, 1, 64);                         \
        }                                                                   \
        double r2_[2];                                                      \
        _Pragma("unroll")                                                   \
        for (int i_ = 0; i_ < 2; ++i_) {                                    \
            const double snd_ = b1 ? r_[2 * i_] : r_[2 * i_ + 1];           \
            const double kp_  = b1 ? r_[2 * i_ + 1] : r_[2 * i_];           \
            r2_[i_] = kp_ + __shfl_xor(snd_, 2, 64);                        \
        }                                                                   \
        const double snd_ = b2 ? r2_[0] : r2_[1];                           \
        const double kp_  = b2 ? r2_[1] : r2_[0];                           \
        double s_ = kp_ + __shfl_xor(snd_, 4, 64);                          \
        s_ += __shfl_xor(s_, 8, 64);                                        \
        s_ += __shfl_xor(s_, 16, 64);                                       \
        s_ += __shfl_xor(s_, 32, 64);                                       \
        s_ += bsel;                                                         \
        if ((T) == lsel) zst = s_;                                          \
        const float sf_ = (float)s_;                                        \
        const float dA_ = cA - sf_;                                         \
        kA += __expf(dA_ * dA_ * -2.0f);                                    \
        const float dB_ = cB - sf_;                                         \
        const float eB_ = __expf(dB_ * dB_ * -2.0f);                        \
        if (hasB) kB += eB_;                                                \
    }

    double accA[NDIM], accB[NDIM];
    float4 d0, d1, d2, e0, e1, e2;

    // prologue: tokens 0 and 1 (FMA(tok1) and COLLAPSE(tok0) share a BB)
    ZLOAD(d0, d1, d2, 0)
    ZLOAD(e0, e1, e2, 1)
    FMATOK(d0, d1, d2, accA)                 // token 0
    ZLOAD(d0, d1, d2, 2)
    FMATOK(e0, e1, e2, accB)                 // token 1  } interleaved by
    COLLAPSE(accA, 0)                        // token 0  } scheduler

    // steady state: pairs (2,3), (4,5), (6,7); branch-free body
#pragma unroll 1
    for (int p = 1; p < 4; ++p) {
        const int tA = 2 * p;                // token in accA this iter
        ZLOAD(e0, e1, e2, tA + 1)
        FMATOK(d0, d1, d2, accA)             // token 2p   } mix
        COLLAPSE(accB, tA - 1)               // token 2p-1 } mix
        const int tn = tA + 2 < 8 ? tA + 2 : 7;   // dead load on last iter
        ZLOAD(d0, d1, d2, tn)
        FMATOK(e0, e1, e2, accB)             // token 2p+1 } mix
        COLLAPSE(accA, tA)                   // token 2p   } mix
    }
    COLLAPSE(accB, 7)

#undef ZLOAD
#undef FMATOK
#undef COLLAPSE

    // stash zc: lane -> token base+lsel, dim dsel (64B per row head)
    __builtin_memcpy(out + (size_t)(base + lsel) * CIN + 2 * dsel, &zst, 8);

    // block reduce (4 waves, identical lane mapping) in f32, slotted f64 atomics
    __shared__ float sAl[256];
    __shared__ float sBl[256];
    sAl[threadIdx.x] = kA;
    sBl[threadIdx.x] = kB;
    __syncthreads();
    if (threadIdx.x < 64) {
        const float rA = sAl[threadIdx.x] + sAl[threadIdx.x + 64] +
                         sAl[threadIdx.x + 128] + sAl[threadIdx.x + 192];
        const float rB = sBl[threadIdx.x] + sBl[threadIdx.x + 64] +
                         sBl[threadIdx.x + 128] + sBl[threadIdx.x + 192];
        const int d = threadIdx.x & 7, l = threadIdx.x >> 3;
        double* slot = kde_slots + (blockIdx.x & (NSLOT - 1)) * 128;
        unsafeAtomicAdd(&slot[d * NLVL + l], (double)rA);
        if (l < 7) unsafeAtomicAdd(&slot[d * NLVL + 8 + l], (double)rB);
    }
}

// ---------------------------------------------------------------------------
// Kernel C: recompute scaled centers in LDS (fused scale step), f64 argmin
// per (token, dim), fp32 expand z_q = q @ We^T + be. Reads zc from the row
// heads this wave later overwrites (load-before-store within the wave).
// launch_bounds(256,2): We's 96-reg array fits the 128 cap (proven rounds
// 0-4, ~40us vs ~31us write floor). Unchanged.
// ---------------------------------------------------------------------------
__global__ __launch_bounds__(256, 2)
void fsq_quant_expand(const double* __restrict__ kde_slots,
                      const float* __restrict__ centers,
                      const float* __restrict__ We, const float* __restrict__ be,
                      float* out, float* out_scalar)
{
    __shared__ double w_lds[NDIM * NLVL];
    __shared__ double sc_lds[NDIM * NLVL];
    {
        const int t = threadIdx.x;
        if (t < NDIM * NLVL) {
            double a = 0.0;
#pragma unroll
            for (int k = 0; k < NSLOT; ++k) a += kde_slots[k * 128 + t];
            w_lds[t] = a * (1.0 / 65536.0) + 1e-6;
        }
        __syncthreads();
        if (t < NDIM * NLVL) {
            const int d = t / NLVL;
            double s = 0.0;
#pragma unroll
            for (int l = 0; l < NLVL; ++l) s += w_lds[d * NLVL + l];
            sc_lds[t] = (double)centers[t] * (w_lds[t] / s);
        }
        if (blockIdx.x == 0 && t == 0) *out_scalar = 0.0f;
        __syncthreads();
    }

    const int lane  = threadIdx.x & 63;
    const int gwave = blockIdx.x * 4 + (threadIdx.x >> 6);
    const int base  = gwave * 8;

    // We in fp32 regs: channel c = lane*4 + 256*m + k
    float Wer[12][NDIM];
    float ber[12];
#pragma unroll
    for (int m = 0; m < 3; ++m) {
#pragma unroll
        for (int k = 0; k < 4; ++k) {
            const int    c  = lane * 4 + 256 * m + k;
            const float4 u0 = *(const float4*)(We + c * NDIM);
            const float4 u1 = *(const float4*)(We + c * NDIM + 4);
            Wer[m * 4 + k][0] = u0.x; Wer[m * 4 + k][1] = u0.y;
            Wer[m * 4 + k][2] = u0.z; Wer[m * 4 + k][3] = u0.w;
            Wer[m * 4 + k][4] = u1.x; Wer[m * 4 + k][5] = u1.y;
            Wer[m * 4 + k][6] = u1.z; Wer[m * 4 + k][7] = u1.w;
            ber[m * 4 + k] = be[c];
        }
    }

    const int dsel = lane & 7;      // this lane's dim
    const int tsel = lane >> 3;     // this lane's token within the group of 8

    // one zc value per lane: (token base+tsel, dim dsel) — before any store
    double zd;
    __builtin_memcpy(&zd, out + (size_t)(base + tsel) * CIN + 2 * dsel, 8);

    // first-min argmin over the 15 scaled centers of dim dsel (matches np)
    const double* sc = sc_lds + dsel * NLVL;
    double best = fabs(zd - sc[0]);
    double q    = sc[0];
#pragma unroll
    for (int l = 1; l < NLVL; ++l) {
        const double dd = fabs(zd - sc[l]);
        if (dd < best) { best = dd; q = sc[l]; }
    }
    const float qf = (float)q;

#pragma unroll 1
    for (int t = 0; t < 8; ++t) {
        float qa[NDIM];
#pragma unroll
        for (int j = 0; j < NDIM; ++j) qa[j] = __shfl(qf, t * 8 + j, 64);

        float* op = out + (size_t)(base + t) * CIN;
#pragma unroll
        for (int m = 0; m < 3; ++m) {
            float v[4];
#pragma unroll
            for (int k = 0; k < 4; ++k) {
                float s = ber[m * 4 + k];
#pragma unroll
                for (int j = 0; j < NDIM; ++j)
                    s = fmaf(qa[j], Wer[m * 4 + k][j], s);
                v[k] = s;
            }
            *(float4*)(op + m * 256 + lane * 4) = make_float4(v[0], v[1], v[2], v[3]);
        }
    }
}

// ---------------------------------------------------------------------------
extern "C" void kernel_launch(void* const* d_in, const int* in_sizes, int n_in,
                              void* d_out, int out_size, void* d_ws, size_t ws_size,
                              hipStream_t stream)
{
    const float* z       = (const float*)d_in[0];
    const float* Wc      = (const float*)d_in[1];
    const float* bc      = (const float*)d_in[2];
    const float* We      = (const float*)d_in[3];
    const float* be      = (const float*)d_in[4];
    const float* centers = (const float*)d_in[5];
    float*       out     = (float*)d_out;

    double* kde_slots = (double*)d_ws;   // NSLOT x 128 doubles = 8 KB

    hipMemsetAsync(kde_slots, 0, NSLOT * 128 * sizeof(double), stream);
    fsq_compress_kde<<<2048, 256, 0, stream>>>(z, Wc, bc, centers, out, kde_slots);
    fsq_quant_expand<<<2048, 256, 0, stream>>>(kde_slots, centers, We, be, out,
                                               out + (size_t)out_size - 1);
}